// Round 13
// baseline (422.819 us; speedup 1.0000x reference)
//
#include <hip/hip_runtime.h>

#define NNODES 50000
#define HID 128
#define NREL 9
#define NLAYERS 3
#define NEDGES 600000

#define NBINS (NREL * NNODES)          // 450000, bin = d*9+r
#define SCAN_CHUNK 1024
#define NBLK ((NBINS + SCAN_CHUNK - 1) / SCAN_CHUNK)   // 440

#define KTOT (NREL * HID)               // 1152
#define GM2 64                          // GEMM M-tile
#define BK 64                           // K-chunk (shorts)
#define NCHUNK (KTOT / BK)              // 18
#define PITCH 72                        // LDS pitch (shorts): 144 B rows -> 2-way banks (free)
#define EPITCH 136                      // epilogue LDS pitch

// prep_kernel block ranges
#define HIST_BLKS ((NEDGES + 255) / 256)            // 2344
#define EMB_BLKS  ((NNODES * HID / 8) / 256)        // 3125
#define W_BLKS    (NLAYERS * NREL)                  // 27

typedef __attribute__((ext_vector_type(8))) short short8;
typedef __attribute__((ext_vector_type(4))) float f32x4;

__device__ __forceinline__ short f2bf(float f) {
    union { float f; unsigned u; } c; c.f = f;
    unsigned r = c.u + 0x7fff + ((c.u >> 16) & 1);   // RNE
    return (short)(r >> 16);
}
__device__ __forceinline__ float bf2f(short v) {
    return __uint_as_float(((unsigned)(unsigned short)v) << 16);
}

// ---------------- prep: histogram + emb convert + W convert (one dispatch) ----------------
// Wt2[l][n][r*128+kk] = bf16(W[l][r][kk][n])

__global__ __launch_bounds__(256) void prep_kernel(const int* __restrict__ dst,
                                                   const int* __restrict__ etype,
                                                   int* __restrict__ bins,
                                                   const float* __restrict__ E,
                                                   short* __restrict__ Ebf,
                                                   const float* __restrict__ W,
                                                   short* __restrict__ Wt2) {
    int b = blockIdx.x, tid = threadIdx.x;
    if (b < HIST_BLKS) {
        int e = b * 256 + tid;
        if (e < NEDGES) {
            int bin = dst[e] * NREL + etype[e];
            atomicAdd(&bins[bin], 1);
        }
    } else if (b < HIST_BLKS + EMB_BLKS) {
        int gid = (b - HIST_BLKS) * 256 + tid;
        const float* p = E + (size_t)gid * 8;
        float4 v0 = *(const float4*)p;
        float4 v1 = *(const float4*)(p + 4);
        short8 o = {f2bf(v0.x), f2bf(v0.y), f2bf(v0.z), f2bf(v0.w),
                    f2bf(v1.x), f2bf(v1.y), f2bf(v1.z), f2bf(v1.w)};
        *(short8*)(Ebf + (size_t)gid * 8) = o;
    } else {
        int lr = b - HIST_BLKS - EMB_BLKS;
        int l = lr / NREL, r = lr - l * NREL;
        const float* w = W + (size_t)lr * HID * HID;
        short* o = Wt2 + (size_t)l * HID * KTOT;
#pragma unroll 4
        for (int i = 0; i < 64; i++) {
            int elem = i * 256 + tid;
            int kk = elem >> 7, n = elem & 127;
            o[(size_t)n * KTOT + r * HID + kk] = f2bf(w[elem]);
        }
    }
}

// ---------------- scans (round-0 verbatim) ----------------

__global__ __launch_bounds__(256) void scan_pass1(const int* __restrict__ bins,
                                                  int* __restrict__ blocksum) {
    __shared__ int red[256];
    int b = blockIdx.x, t = threadIdx.x;
    int i0 = b * SCAN_CHUNK + t * 4;
    int s = 0;
#pragma unroll
    for (int k = 0; k < 4; k++)
        if (i0 + k < NBINS) s += bins[i0 + k];
    red[t] = s;
    __syncthreads();
    for (int off = 128; off > 0; off >>= 1) {
        if (t < off) red[t] += red[t + off];
        __syncthreads();
    }
    if (t == 0) blocksum[b] = red[0];
}

__global__ __launch_bounds__(512) void scan_pass2(const int* __restrict__ blocksum,
                                                  int* __restrict__ blockoff,
                                                  int* __restrict__ rowptr) {
    __shared__ int s[512];
    int t = threadIdx.x;
    int v = (t < NBLK) ? blocksum[t] : 0;
    s[t] = v;
    __syncthreads();
    for (int off = 1; off < 512; off <<= 1) {
        int x = (t >= off) ? s[t - off] : 0;
        __syncthreads();
        s[t] += x;
        __syncthreads();
    }
    if (t < NBLK) blockoff[t] = s[t] - v;
    if (t == 0) rowptr[NBINS] = NEDGES;
}

__global__ __launch_bounds__(256) void scan_pass3(const int* __restrict__ bins,
                                                  const int* __restrict__ blockoff,
                                                  int* __restrict__ rowptr,
                                                  int* __restrict__ cursor) {
    __shared__ int sc[256];
    int b = blockIdx.x, t = threadIdx.x;
    int i0 = b * SCAN_CHUNK + t * 4;
    int v[4], p[4];
    int s = 0;
#pragma unroll
    for (int k = 0; k < 4; k++) {
        v[k] = (i0 + k < NBINS) ? bins[i0 + k] : 0;
        p[k] = s;
        s += v[k];
    }
    sc[t] = s;
    __syncthreads();
    for (int off = 1; off < 256; off <<= 1) {
        int x = (t >= off) ? sc[t - off] : 0;
        __syncthreads();
        sc[t] += x;
        __syncthreads();
    }
    int base = blockoff[b] + (sc[t] - s);
#pragma unroll
    for (int k = 0; k < 4; k++) {
        if (i0 + k < NBINS) {
            rowptr[i0 + k] = base + p[k];
            cursor[i0 + k] = base + p[k];
        }
    }
}

__global__ void place_kernel(const int* __restrict__ dst, const int* __restrict__ src,
                             const int* __restrict__ etype,
                             int* __restrict__ cursor, int* __restrict__ bsrc) {
    int e = blockIdx.x * blockDim.x + threadIdx.x;
    if (e < NEDGES) {
        int bin = dst[e] * NREL + etype[e];
        int pos = atomicAdd(&cursor[bin], 1);
        bsrc[pos] = src[e];
    }
}

// ---------------- gather (round-11 verbatim): S[bin][0..127] = sum_{e in CSR(bin)} Hbf[src_e] ----------------

__global__ __launch_bounds__(256) void gather_kernel(const short* __restrict__ Hbf,
                                                     const int* __restrict__ bsrc,
                                                     const int* __restrict__ rowptr,
                                                     short* __restrict__ S) {
    int gid = blockIdx.x * blockDim.x + threadIdx.x;
    int bin = gid >> 3;
    if (bin >= NBINS) return;
    int ck  = gid & 7;            // 16 cols each
    int rs = rowptr[bin];
    int re = rowptr[bin + 1];
    float a[16];
#pragma unroll
    for (int i = 0; i < 16; i++) a[i] = 0.f;
    for (int j = rs; j < re; j++) {
        int s = bsrc[j];
        const short* hp = Hbf + (size_t)s * HID + ck * 16;
        short8 v0 = *(const short8*)hp;
        short8 v1 = *(const short8*)(hp + 8);
#pragma unroll
        for (int i = 0; i < 8; i++) a[i]     += bf2f(v0[i]);
#pragma unroll
        for (int i = 0; i < 8; i++) a[i + 8] += bf2f(v1[i]);
    }
    short8 o0 = {f2bf(a[0]),  f2bf(a[1]),  f2bf(a[2]),  f2bf(a[3]),
                 f2bf(a[4]),  f2bf(a[5]),  f2bf(a[6]),  f2bf(a[7])};
    short8 o1 = {f2bf(a[8]),  f2bf(a[9]),  f2bf(a[10]), f2bf(a[11]),
                 f2bf(a[12]), f2bf(a[13]), f2bf(a[14]), f2bf(a[15])};
    short* sp = S + (size_t)bin * HID + ck * 16;
    *(short8*)sp       = o0;
    *(short8*)(sp + 8) = o1;
}

// ---------------- gemm: A-only LDS dbuf, 1 barrier/chunk, B direct from L2 ----------------
// Wave shape 64M x 32N (wave owns disjoint 32 N-cols -> B total bytes unchanged,
// B LDS staging + its bank conflicts eliminated). Per phase (chunk kc):
//   MFMA from As[kc&1] (+ parity B regs) -> stage As[(kc+1)&1] from 2-deep-prefetched
//   A regs -> reload A regs (chunk kc+3) and B regs (chunk kc+2) -> ONE barrier.
// Write of chunk k+2 into a buffer is separated from chunk k's reads by the
// intervening barrier -> race-free. 18 barriers vs round-11's 36.
// C mapping (verified, round-5 form): row = mt*16+lq*4+reg, col = wave*32+nt*16+lm.

__global__ __launch_bounds__(256) void gemm_kernel(const short* __restrict__ S,
                                                   const short* __restrict__ Wt2l,
                                                   const float* __restrict__ Bias, // [9][128]
                                                   const int* __restrict__ rowptr,
                                                   short* __restrict__ HoutBf,     // !last: bf16+relu
                                                   float* __restrict__ HoutF,      // last: fp32
                                                   int last) {
    __shared__ short lds[2 * GM2 * PITCH];        // A dbuf (9216 shorts); reused as Et[64][136]
    __shared__ int   rp_s[GM2 * NREL + 1];
    __shared__ float bias_s[NREL * HID];
    short* As0 = lds;
    short* As1 = lds + GM2 * PITCH;

    int tid  = threadIdx.x;
    int wave = tid >> 6, lane = tid & 63;
    int row0 = blockIdx.x * GM2;
    int lm = lane & 15, lq = lane >> 4;

    int rpbase = row0 * NREL;
    for (int i = tid; i <= GM2 * NREL; i += 256) {
        int g = rpbase + i;
        rp_s[i] = rowptr[(g < NBINS) ? g : NBINS];
    }
    for (int i = tid; i < NREL * HID; i += 256) bias_s[i] = Bias[i];

    // A staging mapping: thread (rowL, ck) owns rows rowL & rowL+32, cols ck*8..+8
    int rowL = tid >> 3;          // 0..31
    int ck   = tid & 7;
    int ar0 = row0 + rowL;        if (ar0 > NNODES - 1) ar0 = NNODES - 1;
    int ar1 = row0 + 32 + rowL;   if (ar1 > NNODES - 1) ar1 = NNODES - 1;
    const short* pA0 = S + (size_t)ar0 * KTOT + ck * 8;
    const short* pA1 = S + (size_t)ar1 * KTOT + ck * 8;

    // B per-wave base: rows wave*32 + nt*16 + lm, k-offset kc*BK + ks*32 + lq*8
    const short* wb = Wt2l + (size_t)(wave * 32 + lm) * KTOT + lq * 8;

    // ---- prologue: chunk 0 -> As0; B regs c0 (E) & c1 (O); A regs c1 (O) & c2 (E) ----
    short8 aE0 = *(const short8*)pA0;
    short8 aE1 = *(const short8*)pA1;
    *(short8*)&As0[ rowL       * PITCH + ck * 8] = aE0;
    *(short8*)&As0[(rowL + 32) * PITCH + ck * 8] = aE1;
    short8 bE[4], bO[4];
#pragma unroll
    for (int nt = 0; nt < 2; nt++)
#pragma unroll
        for (int ks = 0; ks < 2; ks++) {
            bE[nt * 2 + ks] = *(const short8*)(wb + (size_t)nt * 16 * KTOT + 0 * BK + ks * 32);
            bO[nt * 2 + ks] = *(const short8*)(wb + (size_t)nt * 16 * KTOT + 1 * BK + ks * 32);
        }
    short8 aO0 = *(const short8*)(pA0 + BK);
    short8 aO1 = *(const short8*)(pA1 + BK);
    aE0 = *(const short8*)(pA0 + 2 * BK);      // slot E now prefetches chunk 2
    aE1 = *(const short8*)(pA1 + 2 * BK);

    f32x4 acc[4][2];
#pragma unroll
    for (int mt = 0; mt < 4; mt++)
#pragma unroll
        for (int nt = 0; nt < 2; nt++) acc[mt][nt] = (f32x4){0.f, 0.f, 0.f, 0.f};

    __syncthreads();

    for (int kp = 0; kp < NCHUNK / 2; kp++) {
        int ke = 2 * kp;
        // ======== even phase: chunk ke from As0 + bE ========
#pragma unroll
        for (int ks = 0; ks < 2; ks++) {
            short8 af0 = *(const short8*)&As0[(lm     ) * PITCH + ks * 32 + lq * 8];
            short8 af1 = *(const short8*)&As0[(lm + 16) * PITCH + ks * 32 + lq * 8];
            short8 af2 = *(const short8*)&As0[(lm + 32) * PITCH + ks * 32 + lq * 8];
            short8 af3 = *(const short8*)&As0[(lm + 48) * PITCH + ks * 32 + lq * 8];
#pragma unroll
            for (int nt = 0; nt < 2; nt++) {
                acc[0][nt] = __builtin_amdgcn_mfma_f32_16x16x32_bf16(af0, bE[nt * 2 + ks], acc[0][nt], 0, 0, 0);
                acc[1][nt] = __builtin_amdgcn_mfma_f32_16x16x32_bf16(af1, bE[nt * 2 + ks], acc[1][nt], 0, 0, 0);
                acc[2][nt] = __builtin_amdgcn_mfma_f32_16x16x32_bf16(af2, bE[nt * 2 + ks], acc[2][nt], 0, 0, 0);
                acc[3][nt] = __builtin_amdgcn_mfma_f32_16x16x32_bf16(af3, bE[nt * 2 + ks], acc[3][nt], 0, 0, 0);
            }
        }
        // stage chunk ke+1 (always exists) into As1; refill aO (ke+3), bE (ke+2)
        *(short8*)&As1[ rowL       * PITCH + ck * 8] = aO0;
        *(short8*)&As1[(rowL + 32) * PITCH + ck * 8] = aO1;
        if (ke + 3 < NCHUNK) {
            aO0 = *(const short8*)(pA0 + (ke + 3) * BK);
            aO1 = *(const short8*)(pA1 + (ke + 3) * BK);
        }
        if (ke + 2 < NCHUNK) {
#pragma unroll
            for (int nt = 0; nt < 2; nt++)
#pragma unroll
                for (int ks = 0; ks < 2; ks++)
                    bE[nt * 2 + ks] = *(const short8*)(wb + (size_t)nt * 16 * KTOT + (ke + 2) * BK + ks * 32);
        }
        __syncthreads();
        // ======== odd phase: chunk ke+1 from As1 + bO ========
#pragma unroll
        for (int ks = 0; ks < 2; ks++) {
            short8 af0 = *(const short8*)&As1[(lm     ) * PITCH + ks * 32 + lq * 8];
            short8 af1 = *(const short8*)&As1[(lm + 16) * PITCH + ks * 32 + lq * 8];
            short8 af2 = *(const short8*)&As1[(lm + 32) * PITCH + ks * 32 + lq * 8];
            short8 af3 = *(const short8*)&As1[(lm + 48) * PITCH + ks * 32 + lq * 8];
#pragma unroll
            for (int nt = 0; nt < 2; nt++) {
                acc[0][nt] = __builtin_amdgcn_mfma_f32_16x16x32_bf16(af0, bO[nt * 2 + ks], acc[0][nt], 0, 0, 0);
                acc[1][nt] = __builtin_amdgcn_mfma_f32_16x16x32_bf16(af1, bO[nt * 2 + ks], acc[1][nt], 0, 0, 0);
                acc[2][nt] = __builtin_amdgcn_mfma_f32_16x16x32_bf16(af2, bO[nt * 2 + ks], acc[2][nt], 0, 0, 0);
                acc[3][nt] = __builtin_amdgcn_mfma_f32_16x16x32_bf16(af3, bO[nt * 2 + ks], acc[3][nt], 0, 0, 0);
            }
        }
        // stage chunk ke+2 into As0; refill aE (ke+4), bO (ke+3)
        if (ke + 2 < NCHUNK) {
            *(short8*)&As0[ rowL       * PITCH + ck * 8] = aE0;
            *(short8*)&As0[(rowL + 32) * PITCH + ck * 8] = aE1;
        }
        if (ke + 4 < NCHUNK) {
            aE0 = *(const short8*)(pA0 + (ke + 4) * BK);
            aE1 = *(const short8*)(pA1 + (ke + 4) * BK);
        }
        if (ke + 3 < NCHUNK) {
#pragma unroll
            for (int nt = 0; nt < 2; nt++)
#pragma unroll
                for (int ks = 0; ks < 2; ks++)
                    bO[nt * 2 + ks] = *(const short8*)(wb + (size_t)nt * 16 * KTOT + (ke + 3) * BK + ks * 32);
        }
        __syncthreads();
    }

    // ---- epilogue: counts-weighted bias, activation, store ----
    // C mapping: row = mt*16 + lq*4 + reg, col = wave*32 + nt*16 + lm
    if (!last) {
        short (*Et)[EPITCH] = (short(*)[EPITCH])lds;
#pragma unroll
        for (int mt = 0; mt < 4; mt++) {
#pragma unroll
            for (int reg = 0; reg < 4; reg++) {
                int rl = mt * 16 + lq * 4 + reg;
                float cr[NREL];
#pragma unroll
                for (int r = 0; r < NREL; r++)
                    cr[r] = (float)(rp_s[rl * NREL + r + 1] - rp_s[rl * NREL + r]);
#pragma unroll
                for (int nt = 0; nt < 2; nt++) {
                    int n = wave * 32 + nt * 16 + lm;
                    float b = 0.f;
#pragma unroll
                    for (int r = 0; r < NREL; r++) b += cr[r] * bias_s[r * HID + n];
                    float o = fmaxf(acc[mt][nt][reg] + b, 0.f);
                    Et[rl][n] = f2bf(o);
                }
            }
        }
        __syncthreads();
#pragma unroll
        for (int i = 0; i < 4; i++) {
            int p = i * 256 + tid;
            int row = p >> 4, cc = p & 15;
            int d = row0 + row;
            if (d < NNODES)
                *(short8*)(HoutBf + (size_t)d * HID + cc * 8) = *(const short8*)&Et[row][cc * 8];
        }
    } else {
#pragma unroll
        for (int mt = 0; mt < 4; mt++) {
#pragma unroll
            for (int reg = 0; reg < 4; reg++) {
                int rl = mt * 16 + lq * 4 + reg;
                int d  = row0 + rl;
                if (d >= NNODES) continue;
                float cr[NREL];
#pragma unroll
                for (int r = 0; r < NREL; r++)
                    cr[r] = (float)(rp_s[rl * NREL + r + 1] - rp_s[rl * NREL + r]);
#pragma unroll
                for (int nt = 0; nt < 2; nt++) {
                    int n = wave * 32 + nt * 16 + lm;
                    float b = 0.f;
#pragma unroll
                    for (int r = 0; r < NREL; r++) b += cr[r] * bias_s[r * HID + n];
                    HoutF[(size_t)d * HID + n] = acc[mt][nt][reg] + b;
                }
            }
        }
    }
}

// ---------------- driver ----------------

extern "C" void kernel_launch(void* const* d_in, const int* in_sizes, int n_in,
                              void* d_out, int out_size, void* d_ws, size_t ws_size,
                              hipStream_t stream) {
    const int*   edge_index = (const int*)d_in[0];   // [2, NEDGES]: row0=dest, row1=src
    const int*   etype      = (const int*)d_in[1];
    const float* emb        = (const float*)d_in[2];
    const float* W          = (const float*)d_in[3]; // [3,9,128,128]
    const float* Bias       = (const float*)d_in[4]; // [3,9,128]
    float*       out        = (float*)d_out;

    const int* dst  = edge_index;
    const int* srcA = edge_index + NEDGES;

    // ws layout (round-11 verbatim, row-major S)
    short* Ebf = (short*)d_ws;                              // 50000*128 bf16
    short* Hbf = Ebf + (size_t)NNODES * HID;                // 50000*128 bf16
    short* S   = Hbf + (size_t)NNODES * HID;                // 50000*1152 bf16 (115.2 MB)
    short* Wt2 = S + (size_t)NNODES * KTOT;                 // 3*128*1152 bf16
    int*   bsrc     = (int*)(Wt2 + (size_t)NLAYERS * HID * KTOT);
    int*   bins     = bsrc + NEDGES;
    int*   cursor   = bins + NBINS;
    int*   rowptr   = cursor + NBINS;                       // NBINS+1
    int*   blocksum = rowptr + NBINS + 1;
    int*   blockoff = blocksum + NBLK;

    hipMemsetAsync(bins, 0, NBINS * sizeof(int), stream);
    prep_kernel<<<HIST_BLKS + EMB_BLKS + W_BLKS, 256, 0, stream>>>(
        dst, etype, bins, emb, Ebf, W, Wt2);
    scan_pass1<<<NBLK, 256, 0, stream>>>(bins, blocksum);
    scan_pass2<<<1, 512, 0, stream>>>(blocksum, blockoff, rowptr);
    scan_pass3<<<NBLK, 256, 0, stream>>>(bins, blockoff, rowptr, cursor);
    place_kernel<<<(NEDGES + 255) / 256, 256, 0, stream>>>(dst, srcA, etype, cursor, bsrc);

    const short* Hin = Ebf;
    for (int l = 0; l < NLAYERS; l++) {
        gather_kernel<<<(NBINS * 8 + 255) / 256, 256, 0, stream>>>(Hin, bsrc, rowptr, S);
        const short* Wtl = Wt2 + (size_t)l * HID * KTOT;
        const float* Bl  = Bias + (size_t)l * NREL * HID;
        int last = (l + 1 == NLAYERS);
        gemm_kernel<<<(NNODES + GM2 - 1) / GM2, 256, 0, stream>>>(
            S, Wtl, Bl, rowptr, Hbf, out, last);
        Hin = Hbf;
    }
}